// Round 3
// baseline (273.887 us; speedup 1.0000x reference)
//
#include <hip/hip_runtime.h>
#include <hip/hip_bf16.h>

#define BB 4
#define TT 2048
#define CC 768
#define HH 12
#define DD 64
#define MM (BB * TT)      // 8192
#define BH (BB * HH)      // 48

typedef __bf16 bf16_t;
typedef __bf16 bf16x8 __attribute__((ext_vector_type(8)));
typedef __bf16 bf16x4 __attribute__((ext_vector_type(4)));
typedef float f32x4 __attribute__((ext_vector_type(4)));
typedef float f32x16 __attribute__((ext_vector_type(16)));

__device__ __forceinline__ float fast_exp2(float x) {
#if __has_builtin(__builtin_amdgcn_exp2f)
    return __builtin_amdgcn_exp2f(x);
#else
    return exp2f(x);
#endif
}

__device__ __forceinline__ uint32_t pk2(float lo, float hi) {
    bf16_t l = (bf16_t)lo, h = (bf16_t)hi;
    uint16_t lu = __builtin_bit_cast(uint16_t, l);
    uint16_t hu = __builtin_bit_cast(uint16_t, h);
    return ((uint32_t)hu << 16) | lu;
}

// async global->LDS, 16B per lane. LDS dest = uniform base + lane*16 (HW rule);
// global address may scatter per-lane (used for the bank-swizzle).
__device__ __forceinline__ void gload_lds16(const void* g, void* l) {
    __builtin_amdgcn_global_load_lds(
        (const __attribute__((address_space(1))) uint32_t*)g,
        (__attribute__((address_space(3))) uint32_t*)l, 16, 0, 0);
}

// ---------------------------------------------------------------- prep: fused cvt + W transposes + trig table + flag zero
// R11: one launch replaces cvt_f32_bf16 + 2x transpose_cvt (launch-gap theory:
// ~65us residual across R0-R2 at ~10us/launch). Also builds the RoPE cos/sin
// table (f32 [2][32][2048], 512KB, L2-resident) so gemm_qkv's epilogue loads
// instead of computing __sincosf (guide Appendix B: precompute trig on host/
// prep -- on-device trig turns epilogue VALU-bound).
__global__ void prep(const float* __restrict__ x,
                     const float* __restrict__ W_attn, const float* __restrict__ W_proj,
                     bf16_t* __restrict__ xb, bf16_t* __restrict__ WaT, bf16_t* __restrict__ WpT,
                     float* __restrict__ trig, int* __restrict__ flags) {
    int blk = blockIdx.x;
    if (blk < 6144) {
        // x f32 -> bf16, 4 elems/thread
        int tid = blk * 256 + threadIdx.x;
        float4 v = ((const float4*)x)[tid];
        bf16x4 o;
        o[0] = (bf16_t)v.x; o[1] = (bf16_t)v.y; o[2] = (bf16_t)v.z; o[3] = (bf16_t)v.w;
        ((bf16x4*)xb)[tid] = o;
    } else if (blk < 6144 + 1728 + 576) {
        // W[K=768][N] f32 -> WT[N][768] bf16, 32x32 tiles
        bool isA = blk < 6144 + 1728;
        int blk2 = blk - (isA ? 6144 : 6144 + 1728);
        const float* W = isA ? W_attn : W_proj;
        bf16_t* WT = isA ? WaT : WpT;
        int N = isA ? 2304 : 768;
        int k0 = (blk2 % 24) * 32, n0 = (blk2 / 24) * 32;
        __shared__ bf16_t tile[32][33];
        int tx = threadIdx.x & 31, ty = threadIdx.x >> 5;
#pragma unroll
        for (int r = 0; r < 4; ++r) {
            int kl = ty * 4 + r;
            tile[kl][tx] = (bf16_t)W[(size_t)(k0 + kl) * N + n0 + tx];
        }
        __syncthreads();
#pragma unroll
        for (int r = 0; r < 4; ++r) {
            int nl = ty * 4 + r;
            WT[(size_t)(n0 + nl) * 768 + k0 + tx] = tile[tx][nl];
        }
    } else {
        // trig table: trig[d*2048+t]=cos(t*infr(d)), trig[65536+...]=sin
        int e = (blk - (6144 + 1728 + 576)) * 1024 + threadIdx.x * 4;
        int d = e >> 11, t0 = e & 2047;
        float infr = exp2f(-(float)d * 0.4152410118609828f);  // 10000^(-d/32)
#pragma unroll
        for (int r = 0; r < 4; ++r) {
            float fr = (float)(t0 + r) * infr;
            float sn, cs;
            sincosf(fr, &sn, &cs);
            trig[d * 2048 + t0 + r] = cs;
            trig[65536 + d * 2048 + t0 + r] = sn;
        }
        if (e < 192 * 4) {   // first blocks also zero the split-k flags
            if (threadIdx.x < 192) flags[threadIdx.x] = 0;
        }
    }
}

// ================================================================ shared GEMM core (R7-verified)
#define GEMM_CORE(A_, BT_, acc_)                                                       \
    __shared__ bf16_t As[2][128 * 32];                                                 \
    __shared__ bf16_t Bs[2][128 * 32];                                                 \
    int tid = threadIdx.x;                                                             \
    int wv = tid >> 6, lane = tid & 63, c = lane & 15, quad = lane >> 4;               \
    int wm = (wv >> 1) * 64, wn = (wv & 1) * 64;                                       \
    int m0 = blockIdx.x * 128, n0 = blockIdx.y * 128;                                  \
    int srow = wv * 32 + (lane >> 2);                                                  \
    int slot = lane & 3;                                                               \
    auto stage = [&](int buf, int k0) {                                                \
        _Pragma("unroll")                                                              \
        for (int ins = 0; ins < 2; ++ins) {                                            \
            int r = srow + ins * 16;                                                   \
            int g = (slot - ((r >> 1) & 3)) & 3;                                       \
            const bf16_t* ga = A_ + (size_t)(m0 + r) * K + k0 + g * 8;                 \
            const bf16_t* gb = BT_ + (size_t)(n0 + r) * K + k0 + g * 8;                \
            gload_lds16(ga, &As[buf][(wv * 32 + ins * 16) * 32]);                      \
            gload_lds16(gb, &Bs[buf][(wv * 32 + ins * 16) * 32]);                      \
        }                                                                              \
    };                                                                                 \
    int s_rd = (quad + ((c >> 1) & 3)) & 3;                                            \
    const int nk = K / 32;                                                             \
    stage(0, 0);                                                                       \
    for (int kt = 0; kt < nk; ++kt) {                                                  \
        __syncthreads();                                                               \
        if (kt + 1 < nk) stage((kt + 1) & 1, (kt + 1) * 32);                           \
        int buf = kt & 1;                                                              \
        bf16x8 af[4], bfr[4];                                                          \
        _Pragma("unroll")                                                              \
        for (int i = 0; i < 4; ++i) af[i] = *(const bf16x8*)&As[buf][(wm + i * 16 + c) * 32 + s_rd * 8];  \
        _Pragma("unroll")                                                              \
        for (int j = 0; j < 4; ++j) bfr[j] = *(const bf16x8*)&Bs[buf][(wn + j * 16 + c) * 32 + s_rd * 8]; \
        _Pragma("unroll")                                                              \
        for (int i = 0; i < 4; ++i)                                                    \
            _Pragma("unroll")                                                          \
            for (int j = 0; j < 4; ++j)                                                \
                acc_[i][j] = __builtin_amdgcn_mfma_f32_16x16x32_bf16(af[i], bfr[j], acc_[i][j], 0, 0, 0); \
    }

// ---------------------------------------------------------------- qkv GEMM, fused bias+rotary+head-split+V-transpose
// R11: rotary via precomputed trig table (f32x4 L2 loads) instead of
// __sincosf; launch_bounds (256,4) -> 4 blocks/CU (VGPR 56, LDS 34.8KB fit).
__global__ __launch_bounds__(256, 4) void gemm_qkv(
        const bf16_t* __restrict__ A, const bf16_t* __restrict__ BT,
        const float* __restrict__ bias, const float* __restrict__ trig,
        bf16_t* __restrict__ Qh, bf16_t* __restrict__ Kh, bf16_t* __restrict__ Vt) {
    const int K = 768;
    __shared__ __align__(16) bf16_t smem[17408];   // stage 32KB, epi 4x(64x68)
    bf16_t* Asp = smem;           // [2][4096]
    bf16_t* Bsp = smem + 8192;    // [2][4096]
    int tid = threadIdx.x;
    int wv = tid >> 6, lane = tid & 63, c = lane & 15, quad = lane >> 4;
    int wm = (wv >> 1) * 64, wn = (wv & 1) * 64;
    int m0 = blockIdx.x * 128, n0 = blockIdx.y * 128;
    int srow = wv * 32 + (lane >> 2);
    int slot = lane & 3;
    auto stage = [&](int buf, int k0) {
#pragma unroll
        for (int ins = 0; ins < 2; ++ins) {
            int r = srow + ins * 16;
            int g = (slot - ((r >> 1) & 3)) & 3;
            gload_lds16(A + (size_t)(m0 + r) * K + k0 + g * 8, &Asp[buf * 4096 + (wv * 32 + ins * 16) * 32]);
            gload_lds16(BT + (size_t)(n0 + r) * K + k0 + g * 8, &Bsp[buf * 4096 + (wv * 32 + ins * 16) * 32]);
        }
    };
    int s_rd = (quad + ((c >> 1) & 3)) & 3;
    f32x4 acc[4][4] = {};
    const int nk = K / 32;
    stage(0, 0);
    for (int kt = 0; kt < nk; ++kt) {
        __syncthreads();
        if (kt + 1 < nk) stage((kt + 1) & 1, (kt + 1) * 32);
        int buf = kt & 1;
        bf16x8 af[4], bfr[4];
#pragma unroll
        for (int i = 0; i < 4; ++i) af[i] = *(const bf16x8*)&Asp[buf * 4096 + (wm + i * 16 + c) * 32 + s_rd * 8];
#pragma unroll
        for (int j = 0; j < 4; ++j) bfr[j] = *(const bf16x8*)&Bsp[buf * 4096 + (wn + j * 16 + c) * 32 + s_rd * 8];
#pragma unroll
        for (int i = 0; i < 4; ++i)
#pragma unroll
            for (int j = 0; j < 4; ++j)
                acc[i][j] = __builtin_amdgcn_mfma_f32_16x16x32_bf16(af[i], bfr[j], acc[i][j], 0, 0, 0);
    }
    __syncthreads();                        // all frag reads done; LDS now epilogue staging

    int type = n0 / 768;                    // 0=Q 1=K 2=V (block-uniform)
    int hloc = ((n0 % 768) + wn) >> 6;      // wave's 64 cols = one head
    int bidx = m0 >> 11;
    int colb = n0 + wn;
    int tb = (m0 + wm) & (TT - 1);          // wave's 64-row t-base (mult of 64)
    bf16_t* epi = smem + wv * 4352;         // 64 rows x 68 (+4 pad breaks bank stride)
    int rrow = lane >> 3, cchunk = lane & 7;

    if (type < 2) {
        const float rscale = (type == 0) ? 0.125f * 1.44269504088896f : 1.0f;
#pragma unroll
        for (int j = 0; j < 2; ++j) {
            int dlo = j * 16 + c;
            const float* ctab = trig + dlo * 2048 + tb;
            const float* stab = trig + 65536 + dlo * 2048 + tb;
            float blo = bias[colb + j * 16 + c];
            float bhi = bias[colb + (j + 2) * 16 + c];
#pragma unroll
            for (int i = 0; i < 4; ++i) {
                f32x4 cs4 = *(const f32x4*)(ctab + i * 16 + quad * 4);
                f32x4 sn4 = *(const f32x4*)(stab + i * 16 + quad * 4);
#pragma unroll
                for (int r = 0; r < 4; ++r) {
                    int lr = i * 16 + quad * 4 + r;
                    float a = acc[i][j][r] + blo;
                    float b2 = acc[i][j + 2][r] + bhi;
                    epi[lr * 68 + dlo]      = (bf16_t)((a * cs4[r] + b2 * sn4[r]) * rscale);
                    epi[lr * 68 + dlo + 32] = (bf16_t)((-a * sn4[r] + b2 * cs4[r]) * rscale);
                }
            }
        }
        bf16_t* dst = (type == 0 ? Qh : Kh) + (size_t)(bidx * HH + hloc) * TT * DD + (size_t)tb * DD;
#pragma unroll
        for (int it = 0; it < 8; ++it) {
            int row = it * 8 + rrow;
            bf16x8 v = *(const bf16x8*)&epi[row * 68 + cchunk * 8];
            *(bf16x8*)&dst[row * 64 + cchunk * 8] = v;    // 1KB/instr, full lines
        }
    } else {
        int kt64 = tb >> 6;
#pragma unroll
        for (int j = 0; j < 4; ++j) {
            int dim = j * 16 + c;
            float bv = bias[colb + j * 16 + c];
            int rot = (dim & 7) * 8;
#pragma unroll
            for (int i = 0; i < 4; ++i)
#pragma unroll
                for (int r = 0; r < 4; ++r) {
                    int tin = i * 16 + quad * 4 + r;
                    epi[dim * 68 + ((tin + rot) & 63)] = (bf16_t)(acc[i][j][r] + bv);
                }
        }
        bf16_t* dstV = Vt + (size_t)(bidx * HH + hloc) * (TT / 64) * 4096 + (size_t)kt64 * 4096;
#pragma unroll
        for (int it = 0; it < 8; ++it) {
            int dim = it * 8 + rrow;
            int src = ((cchunk + (dim & 7)) & 7) * 8;     // un-rotate
            bf16x8 v = *(const bf16x8*)&epi[dim * 68 + src];
            *(bf16x8*)&dstV[dim * 64 + cchunk * 8] = v;   // 1KB/instr, full lines
        }
    }
}

// ---------------------------------------------------------------- proj GEMM: out f32 = Yb @ WpT^T + bias
__global__ __launch_bounds__(256, 4) void gemm_proj(
        const bf16_t* __restrict__ A, const bf16_t* __restrict__ BT,
        const float* __restrict__ bias, float* __restrict__ Cout) {
    const int K = 768;
    f32x4 acc[4][4] = {};
    GEMM_CORE(A, BT, acc)
#pragma unroll
    for (int j = 0; j < 4; ++j) {
        int col = n0 + wn + j * 16 + c;
        float bv = bias[col];
#pragma unroll
        for (int i = 0; i < 4; ++i) {
            int row = m0 + wm + i * 16 + quad * 4;
#pragma unroll
            for (int r = 0; r < 4; ++r)
                Cout[(size_t)(row + r) * CC + col] = acc[i][j][r] + bv;
        }
    }
}

// ---------------------------------------------------------------- flash attention
// R10 structure (equal-work items + dynamic tail) + R11: combine folded in via
// split-k semaphore (partials -> threadfence -> atomicAdd flag; second
// finisher combines; flags zeroed by prep each iteration). Saves one launch.
__constant__ signed char RK_QT[20] = {11,10,9,8,15,15,7,14,14,13,13,6,12,12,5,4,3,2,1,0};
__constant__ signed char RK_PC[20] = { 2, 2,2,2, 0, 1,2, 0, 1, 0, 1,2, 0, 1,2,2,2,2,2,2};

__global__ __launch_bounds__(256, 3) void flash_attn(
        const bf16_t* __restrict__ Q, const bf16_t* __restrict__ Kc,
        const bf16_t* __restrict__ Vt, bf16_t* __restrict__ Y,
        float* __restrict__ Opart, float* __restrict__ Lpart, int* __restrict__ flags) {
    // 43KB declared (32KB used): floor(160/43)=3 blocks/CU -> dynamic tail queue
    __shared__ __align__(16) bf16_t smem[22016];
    bf16_t* KsB = smem;            // [2][64*64]
    bf16_t* VsB = smem + 13824;    // [2][64*64] (placed at pad end; full span referenced)

    int blk = blockIdx.x;
    int r = blk / 48, bh = blk - r * 48;   // rank-major: blk 0..47 are the 24-tile items
    int qt = RK_QT[r], pc = RK_PC[r];      // pc: 0=key-half0, 1=key-half1, 2=full chunk
    int kt0 = (pc == 1) ? (qt + 1) : 0;
    int ktend = (pc == 0) ? (qt + 1) : (2 * qt + 2);
    int nct = ktend - kt0;

    int wv = threadIdx.x >> 6, lane = threadIdx.x & 63;
    int b = bh / HH, h = bh - b * HH;
    int q31 = lane & 31, hi = lane >> 5;
    int qbw = qt * 128 + wv * 32;
    const bf16_t* Qg = Q + ((size_t)bh * TT + qbw) * DD;
    const bf16_t* Kg = Kc + (size_t)bh * TT * DD;
    const bf16_t* Vg = Vt + (size_t)bh * (TT / 64) * 4096;

    // Q B-frag: col=q31, k = dk*16 + hi*8 + i (contiguous d per lane)
    bf16x8 qf[4];
#pragma unroll
    for (int dk = 0; dk < 4; ++dk)
        qf[dk] = *(const bf16x8*)(Qg + (size_t)q31 * DD + dk * 16 + hi * 8);

    int srow = wv * 16 + (lane >> 3);
    int slot = lane & 7;
    auto stage = [&](int buf, int kt64) {
#pragma unroll
        for (int ins = 0; ins < 2; ++ins) {
            int rr = srow + ins * 8;
            int g = (slot - (rr & 7)) & 7;
            gload_lds16(Kg + (size_t)(kt64 * 64 + rr) * 64 + g * 8, &KsB[buf * 4096 + (wv * 16 + ins * 8) * 64]);
            gload_lds16(Vg + (size_t)kt64 * 4096 + rr * 64 + g * 8, &VsB[buf * 4096 + (wv * 16 + ins * 8) * 64]);
        }
    };

    f32x16 O[2] = {};            // O^T: col=query=q31, row(d-local)=(r&3)+8*(r>>2)+4*hi, dt*32 offset
    float lsum = 0.0f;

    stage(0, kt0);

#define FA_TILE(FULL)                                                                   \
    {                                                                                   \
        int kt = kt0 + i;                                                               \
        int buf = i & 1;                                                                \
        __syncthreads();                                                                \
        if (i + 1 < nct) stage((i + 1) & 1, kt + 1);                                    \
        _Pragma("unroll")                                                               \
        for (int t32 = 0; t32 < 2; ++t32) {                                             \
            int ks = kt * 64 + t32 * 32;                                                \
            if (!(FULL) && ks > qbw) continue;                                          \
            bool masked = !(FULL) && (ks == qbw);                                       \
            f32x16 st = {};                                                             \
            __builtin_amdgcn_s_setprio(1);                                              \
            _Pragma("unroll")                                                           \
            for (int dk = 0; dk < 4; ++dk) {                                            \
                int row = t32 * 32 + q31;                                               \
                int sl = ((dk * 2 + hi) + (row & 7)) & 7;                               \
                bf16x8 kf = *(const bf16x8*)&KsB[buf * 4096 + row * 64 + sl * 8];       \
                st = __builtin_amdgcn_mfma_f32_32x32x16_bf16(kf, qf[dk], st, 0, 0, 0);  \
            }                                                                           \
            __builtin_amdgcn_s_setprio(0);                                              \
            bf16x8 vf[2][2];                                                            \
            _Pragma("unroll")                                                           \
            for (int dt = 0; dt < 2; ++dt)                                              \
                _Pragma("unroll")                                                       \
                for (int sli = 0; sli < 2; ++sli) {                                     \
                    int row = dt * 32 + q31;                                            \
                    int ch = t32 * 4 + sli * 2 + hi;                                    \
                    int sl = (ch + (row & 7)) & 7;                                      \
                    vf[dt][sli] = *(const bf16x8*)&VsB[buf * 4096 + row * 64 + sl * 8]; \
                }                                                                       \
            float p[16];                                                                \
            _Pragma("unroll")                                                           \
            for (int rr = 0; rr < 16; ++rr) {                                           \
                float e = fast_exp2(st[rr]);                                            \
                if (masked) {                                                           \
                    int keyl = (rr & 3) + 8 * (rr >> 2) + 4 * hi;                       \
                    if (keyl > q31) e = 0.0f;                                           \
                }                                                                       \
                p[rr] = e;                                                              \
            }                                                                           \
            lsum += ((((p[0] + p[1]) + (p[2] + p[3])) + ((p[4] + p[5]) + (p[6] + p[7])))\
                  + (((p[8] + p[9]) + (p[10] + p[11])) + ((p[12] + p[13]) + (p[14] + p[15])))); \
            union { uint32_t u[4]; bf16x8 v; } pb[2];                                   \
            _Pragma("unroll")                                                           \
            for (int sli = 0; sli < 2; ++sli) {                                         \
                uint32_t a0 = pk2(p[sli * 8 + 0], p[sli * 8 + 1]);                      \
                uint32_t b0 = pk2(p[sli * 8 + 2], p[sli * 8 + 3]);                      \
                uint32_t a1 = pk2(p[sli * 8 + 4], p[sli * 8 + 5]);                      \
                uint32_t b1 = pk2(p[sli * 8 + 6], p[sli * 8 + 7]);                      \
                asm("v_permlane32_swap_b32 %0, %1" : "+v"(a0), "+v"(a1));               \
                asm("v_permlane32_swap_b32 %0, %1" : "+v"(b0), "+v"(b1));               \
                pb[sli].u[0] = a0; pb[sli].u[1] = b0; pb[sli].u[2] = a1; pb[sli].u[3] = b1; \
            }                                                                           \
            __builtin_amdgcn_s_setprio(1);                                              \
            _Pragma("unroll")                                                           \
            for (int dt = 0; dt < 2; ++dt) {                                            \
                O[dt] = __builtin_amdgcn_mfma_f32_32x32x16_bf16(vf[dt][0], pb[0].v, O[dt], 0, 0, 0); \
                O[dt] = __builtin_amdgcn_mfma_f32_32x32x16_bf16(vf[dt][1], pb[1].v, O[dt], 0, 0, 0); \
            }                                                                           \
            __builtin_amdgcn_s_setprio(0);                                              \
        }                                                                               \
    }

    int nfull = 2 * qt - kt0;                 // tiles before any mask possible
    if (nfull > nct) nfull = nct;
    if (nfull < 0) nfull = 0;
    int i = 0;
    for (; i < nfull; ++i) FA_TILE(1)         // branch-free interior
    for (; i < nct; ++i) FA_TILE(0)           // causal boundary (<=2 tiles)
#undef FA_TILE

    float l = lsum;
    l += __shfl_xor(l, 32);                   // partner half-lane holds complementary keys

    if (pc == 2) {
        float inv_l = 1.0f / l;
        int row = b * TT + qbw + q31;
#pragma unroll
        for (int dt = 0; dt < 2; ++dt)
#pragma unroll
            for (int g = 0; g < 4; ++g) {
                bf16x4 ov;
#pragma unroll
                for (int rr = 0; rr < 4; ++rr) ov[rr] = (bf16_t)(O[dt][g * 4 + rr] * inv_l);
                *(bf16x4*)(Y + (size_t)row * CC + h * DD + dt * 32 + g * 8 + hi * 4) = ov;
            }
    } else {
        int pslot = bh * 4 + (qt - 12);       // 0..191
        int idx = pslot * 2 + pc;
        float* Op = Opart + ((size_t)idx * 128 + wv * 32 + q31) * 64;
#pragma unroll
        for (int dt = 0; dt < 2; ++dt)
#pragma unroll
            for (int g = 0; g < 4; ++g) {
                f32x4 ov;
#pragma unroll
                for (int rr = 0; rr < 4; ++rr) ov[rr] = O[dt][g * 4 + rr];
                *(f32x4*)(Op + dt * 32 + g * 8 + hi * 4) = ov;
            }
        if (hi == 0) Lpart[idx * 128 + wv * 32 + q31] = l;

        // split-k semaphore: release our partial, second finisher combines
        __threadfence();                       // make Opart/Lpart visible device-wide
        __syncthreads();                       // all waves' writes+fence done
        __shared__ int win_s;
        if (threadIdx.x == 0)
            win_s = (atomicAdd(&flags[pslot], 1) == 1);
        __syncthreads();
        if (win_s) {
            __threadfence();                   // acquire partner's writes
            int t = threadIdx.x;
            int q = t >> 1, dh = (t & 1) * 32;
            const float* p0 = Opart + ((size_t)(pslot * 2 + 0) * 128 + q) * 64 + dh;
            const float* p1 = Opart + ((size_t)(pslot * 2 + 1) * 128 + q) * 64 + dh;
            float inv = 1.0f / (Lpart[(pslot * 2 + 0) * 128 + q] + Lpart[(pslot * 2 + 1) * 128 + q]);
            bf16_t* y = Y + ((size_t)(b * TT + qt * 128 + q)) * CC + h * DD + dh;
#pragma unroll
            for (int g = 0; g < 4; ++g) {
                f32x4 a  = *(const f32x4*)(p0 + g * 8);
                f32x4 a2 = *(const f32x4*)(p0 + g * 8 + 4);
                f32x4 c1 = *(const f32x4*)(p1 + g * 8);
                f32x4 c2 = *(const f32x4*)(p1 + g * 8 + 4);
                bf16x8 o;
#pragma unroll
                for (int rr = 0; rr < 4; ++rr) o[rr] = (bf16_t)((a[rr] + c1[rr]) * inv);
#pragma unroll
                for (int rr = 0; rr < 4; ++rr) o[4 + rr] = (bf16_t)((a2[rr] + c2[rr]) * inv);
                *(bf16x8*)(y + g * 8) = o;
            }
        }
    }
}

// ---------------------------------------------------------------- launch
extern "C" void kernel_launch(void* const* d_in, const int* in_sizes, int n_in,
                              void* d_out, int out_size, void* d_ws, size_t ws_size,
                              hipStream_t stream) {
    const float* x      = (const float*)d_in[0];
    const float* W_attn = (const float*)d_in[1];
    const float* b_attn = (const float*)d_in[2];
    const float* W_proj = (const float*)d_in[3];
    const float* b_proj = (const float*)d_in[4];
    float* out = (float*)d_out;

    unsigned char* ws = (unsigned char*)d_ws;
    size_t off = 0;
    auto alloc = [&](size_t bytes) { void* p = ws + off; off += (bytes + 255) & ~(size_t)255; return p; };
    bf16_t* xb  = (bf16_t*)alloc((size_t)MM * CC * 2);
    bf16_t* WaT = (bf16_t*)alloc((size_t)3 * CC * CC * 2);
    bf16_t* WpT = (bf16_t*)alloc((size_t)CC * CC * 2);
    bf16_t* Qh  = (bf16_t*)alloc((size_t)BH * TT * DD * 2);
    bf16_t* Kh  = (bf16_t*)alloc((size_t)BH * TT * DD * 2);
    bf16_t* Vt  = (bf16_t*)alloc((size_t)BH * TT * DD * 2);
    bf16_t* Yb  = (bf16_t*)alloc((size_t)MM * CC * 2);
    float*  Opart = (float*)alloc((size_t)192 * 2 * 128 * 64 * 4);
    float*  Lpart = (float*)alloc((size_t)192 * 2 * 128 * 4);
    float*  trig  = (float*)alloc((size_t)2 * 32 * 2048 * 4);
    int*    flags = (int*)alloc((size_t)192 * 4);

    prep<<<dim3(6144 + 1728 + 576 + 64), 256, 0, stream>>>(x, W_attn, W_proj, xb, WaT, WpT, trig, flags);
    gemm_qkv<<<dim3(MM / 128, 3 * CC / 128), 256, 0, stream>>>(xb, WaT, b_attn, trig, Qh, Kh, Vt);
    flash_attn<<<dim3(960), 256, 0, stream>>>(Qh, Kh, Vt, Yb, Opart, Lpart, flags);
    gemm_proj<<<dim3(MM / 128, CC / 128), 256, 0, stream>>>(Yb, WpT, b_proj, out);
}

// Round 4
// 186.786 us; speedup vs baseline: 1.4663x; 1.4663x over previous
//
#include <hip/hip_runtime.h>
#include <hip/hip_bf16.h>

#define BB 4
#define TT 2048
#define CC 768
#define HH 12
#define DD 64
#define MM (BB * TT)      // 8192
#define BH (BB * HH)      // 48

typedef __bf16 bf16_t;
typedef __bf16 bf16x8 __attribute__((ext_vector_type(8)));
typedef __bf16 bf16x4 __attribute__((ext_vector_type(4)));
typedef float f32x4 __attribute__((ext_vector_type(4)));
typedef float f32x16 __attribute__((ext_vector_type(16)));

__device__ __forceinline__ float fast_exp2(float x) {
#if __has_builtin(__builtin_amdgcn_exp2f)
    return __builtin_amdgcn_exp2f(x);
#else
    return exp2f(x);
#endif
}

__device__ __forceinline__ uint32_t pk2(float lo, float hi) {
    bf16_t l = (bf16_t)lo, h = (bf16_t)hi;
    uint16_t lu = __builtin_bit_cast(uint16_t, l);
    uint16_t hu = __builtin_bit_cast(uint16_t, h);
    return ((uint32_t)hu << 16) | lu;
}

// async global->LDS, 16B per lane. LDS dest = uniform base + lane*16 (HW rule);
// global address may scatter per-lane (used for the bank-swizzle).
__device__ __forceinline__ void gload_lds16(const void* g, void* l) {
    __builtin_amdgcn_global_load_lds(
        (const __attribute__((address_space(1))) uint32_t*)g,
        (__attribute__((address_space(3))) uint32_t*)l, 16, 0, 0);
}

// ---------------------------------------------------------------- prep: fused cvt + W transposes + trig table
// R11-kept: one launch replaces cvt_f32_bf16 + 2x transpose_cvt. Builds the
// RoPE cos/sin table (f32 [2][32][2048], 512KB, L2-resident) so gemm_qkv's
// epilogue loads instead of computing __sincosf.
// R12: flags/semaphore REMOVED -- R3 post-mortem: __threadfence() (device-
// scope, L2 writeback on non-coherent per-XCD L2) stretched flash_attn 3x.
__global__ void prep(const float* __restrict__ x,
                     const float* __restrict__ W_attn, const float* __restrict__ W_proj,
                     bf16_t* __restrict__ xb, bf16_t* __restrict__ WaT, bf16_t* __restrict__ WpT,
                     float* __restrict__ trig) {
    int blk = blockIdx.x;
    if (blk < 6144) {
        // x f32 -> bf16, 4 elems/thread
        int tid = blk * 256 + threadIdx.x;
        float4 v = ((const float4*)x)[tid];
        bf16x4 o;
        o[0] = (bf16_t)v.x; o[1] = (bf16_t)v.y; o[2] = (bf16_t)v.z; o[3] = (bf16_t)v.w;
        ((bf16x4*)xb)[tid] = o;
    } else if (blk < 6144 + 1728 + 576) {
        // W[K=768][N] f32 -> WT[N][768] bf16, 32x32 tiles
        bool isA = blk < 6144 + 1728;
        int blk2 = blk - (isA ? 6144 : 6144 + 1728);
        const float* W = isA ? W_attn : W_proj;
        bf16_t* WT = isA ? WaT : WpT;
        int N = isA ? 2304 : 768;
        int k0 = (blk2 % 24) * 32, n0 = (blk2 / 24) * 32;
        __shared__ bf16_t tile[32][33];
        int tx = threadIdx.x & 31, ty = threadIdx.x >> 5;
#pragma unroll
        for (int r = 0; r < 4; ++r) {
            int kl = ty * 4 + r;
            tile[kl][tx] = (bf16_t)W[(size_t)(k0 + kl) * N + n0 + tx];
        }
        __syncthreads();
#pragma unroll
        for (int r = 0; r < 4; ++r) {
            int nl = ty * 4 + r;
            WT[(size_t)(n0 + nl) * 768 + k0 + tx] = tile[tx][nl];
        }
    } else {
        // trig table: trig[d*2048+t]=cos(t*infr(d)), trig[65536+...]=sin
        int e = (blk - (6144 + 1728 + 576)) * 1024 + threadIdx.x * 4;
        int d = e >> 11, t0 = e & 2047;
        float infr = exp2f(-(float)d * 0.4152410118609828f);  // 10000^(-d/32)
#pragma unroll
        for (int r = 0; r < 4; ++r) {
            float fr = (float)(t0 + r) * infr;
            float sn, cs;
            sincosf(fr, &sn, &cs);
            trig[d * 2048 + t0 + r] = cs;
            trig[65536 + d * 2048 + t0 + r] = sn;
        }
    }
}

// ================================================================ shared GEMM core (R7-verified)
#define GEMM_CORE(A_, BT_, acc_)                                                       \
    __shared__ bf16_t As[2][128 * 32];                                                 \
    __shared__ bf16_t Bs[2][128 * 32];                                                 \
    int tid = threadIdx.x;                                                             \
    int wv = tid >> 6, lane = tid & 63, c = lane & 15, quad = lane >> 4;               \
    int wm = (wv >> 1) * 64, wn = (wv & 1) * 64;                                       \
    int m0 = blockIdx.x * 128, n0 = blockIdx.y * 128;                                  \
    int srow = wv * 32 + (lane >> 2);                                                  \
    int slot = lane & 3;                                                               \
    auto stage = [&](int buf, int k0) {                                                \
        _Pragma("unroll")                                                              \
        for (int ins = 0; ins < 2; ++ins) {                                            \
            int r = srow + ins * 16;                                                   \
            int g = (slot - ((r >> 1) & 3)) & 3;                                       \
            const bf16_t* ga = A_ + (size_t)(m0 + r) * K + k0 + g * 8;                 \
            const bf16_t* gb = BT_ + (size_t)(n0 + r) * K + k0 + g * 8;                \
            gload_lds16(ga, &As[buf][(wv * 32 + ins * 16) * 32]);                      \
            gload_lds16(gb, &Bs[buf][(wv * 32 + ins * 16) * 32]);                      \
        }                                                                              \
    };                                                                                 \
    int s_rd = (quad + ((c >> 1) & 3)) & 3;                                            \
    const int nk = K / 32;                                                             \
    stage(0, 0);                                                                       \
    for (int kt = 0; kt < nk; ++kt) {                                                  \
        __syncthreads();                                                               \
        if (kt + 1 < nk) stage((kt + 1) & 1, (kt + 1) * 32);                           \
        int buf = kt & 1;                                                              \
        bf16x8 af[4], bfr[4];                                                          \
        _Pragma("unroll")                                                              \
        for (int i = 0; i < 4; ++i) af[i] = *(const bf16x8*)&As[buf][(wm + i * 16 + c) * 32 + s_rd * 8];  \
        _Pragma("unroll")                                                              \
        for (int j = 0; j < 4; ++j) bfr[j] = *(const bf16x8*)&Bs[buf][(wn + j * 16 + c) * 32 + s_rd * 8]; \
        _Pragma("unroll")                                                              \
        for (int i = 0; i < 4; ++i)                                                    \
            _Pragma("unroll")                                                          \
            for (int j = 0; j < 4; ++j)                                                \
                acc_[i][j] = __builtin_amdgcn_mfma_f32_16x16x32_bf16(af[i], bfr[j], acc_[i][j], 0, 0, 0); \
    }

// ---------------------------------------------------------------- qkv GEMM, fused bias+rotary+head-split+V-transpose
// Rotary via precomputed trig table (f32x4 L2 loads) instead of __sincosf;
// launch_bounds (256,4) -> 4 blocks/CU (VGPR 56, LDS 34.8KB fit).
__global__ __launch_bounds__(256, 4) void gemm_qkv(
        const bf16_t* __restrict__ A, const bf16_t* __restrict__ BT,
        const float* __restrict__ bias, const float* __restrict__ trig,
        bf16_t* __restrict__ Qh, bf16_t* __restrict__ Kh, bf16_t* __restrict__ Vt) {
    const int K = 768;
    __shared__ __align__(16) bf16_t smem[17408];   // stage 32KB, epi 4x(64x68)
    bf16_t* Asp = smem;           // [2][4096]
    bf16_t* Bsp = smem + 8192;    // [2][4096]
    int tid = threadIdx.x;
    int wv = tid >> 6, lane = tid & 63, c = lane & 15, quad = lane >> 4;
    int wm = (wv >> 1) * 64, wn = (wv & 1) * 64;
    int m0 = blockIdx.x * 128, n0 = blockIdx.y * 128;
    int srow = wv * 32 + (lane >> 2);
    int slot = lane & 3;
    auto stage = [&](int buf, int k0) {
#pragma unroll
        for (int ins = 0; ins < 2; ++ins) {
            int r = srow + ins * 16;
            int g = (slot - ((r >> 1) & 3)) & 3;
            gload_lds16(A + (size_t)(m0 + r) * K + k0 + g * 8, &Asp[buf * 4096 + (wv * 32 + ins * 16) * 32]);
            gload_lds16(BT + (size_t)(n0 + r) * K + k0 + g * 8, &Bsp[buf * 4096 + (wv * 32 + ins * 16) * 32]);
        }
    };
    int s_rd = (quad + ((c >> 1) & 3)) & 3;
    f32x4 acc[4][4] = {};
    const int nk = K / 32;
    stage(0, 0);
    for (int kt = 0; kt < nk; ++kt) {
        __syncthreads();
        if (kt + 1 < nk) stage((kt + 1) & 1, (kt + 1) * 32);
        int buf = kt & 1;
        bf16x8 af[4], bfr[4];
#pragma unroll
        for (int i = 0; i < 4; ++i) af[i] = *(const bf16x8*)&Asp[buf * 4096 + (wm + i * 16 + c) * 32 + s_rd * 8];
#pragma unroll
        for (int j = 0; j < 4; ++j) bfr[j] = *(const bf16x8*)&Bsp[buf * 4096 + (wn + j * 16 + c) * 32 + s_rd * 8];
#pragma unroll
        for (int i = 0; i < 4; ++i)
#pragma unroll
            for (int j = 0; j < 4; ++j)
                acc[i][j] = __builtin_amdgcn_mfma_f32_16x16x32_bf16(af[i], bfr[j], acc[i][j], 0, 0, 0);
    }
    __syncthreads();                        // all frag reads done; LDS now epilogue staging

    int type = n0 / 768;                    // 0=Q 1=K 2=V (block-uniform)
    int hloc = ((n0 % 768) + wn) >> 6;      // wave's 64 cols = one head
    int bidx = m0 >> 11;
    int colb = n0 + wn;
    int tb = (m0 + wm) & (TT - 1);          // wave's 64-row t-base (mult of 64)
    bf16_t* epi = smem + wv * 4352;         // 64 rows x 68 (+4 pad breaks bank stride)
    int rrow = lane >> 3, cchunk = lane & 7;

    if (type < 2) {
        const float rscale = (type == 0) ? 0.125f * 1.44269504088896f : 1.0f;
#pragma unroll
        for (int j = 0; j < 2; ++j) {
            int dlo = j * 16 + c;
            const float* ctab = trig + dlo * 2048 + tb;
            const float* stab = trig + 65536 + dlo * 2048 + tb;
            float blo = bias[colb + j * 16 + c];
            float bhi = bias[colb + (j + 2) * 16 + c];
#pragma unroll
            for (int i = 0; i < 4; ++i) {
                f32x4 cs4 = *(const f32x4*)(ctab + i * 16 + quad * 4);
                f32x4 sn4 = *(const f32x4*)(stab + i * 16 + quad * 4);
#pragma unroll
                for (int r = 0; r < 4; ++r) {
                    int lr = i * 16 + quad * 4 + r;
                    float a = acc[i][j][r] + blo;
                    float b2 = acc[i][j + 2][r] + bhi;
                    epi[lr * 68 + dlo]      = (bf16_t)((a * cs4[r] + b2 * sn4[r]) * rscale);
                    epi[lr * 68 + dlo + 32] = (bf16_t)((-a * sn4[r] + b2 * cs4[r]) * rscale);
                }
            }
        }
        bf16_t* dst = (type == 0 ? Qh : Kh) + (size_t)(bidx * HH + hloc) * TT * DD + (size_t)tb * DD;
#pragma unroll
        for (int it = 0; it < 8; ++it) {
            int row = it * 8 + rrow;
            bf16x8 v = *(const bf16x8*)&epi[row * 68 + cchunk * 8];
            *(bf16x8*)&dst[row * 64 + cchunk * 8] = v;    // 1KB/instr, full lines
        }
    } else {
        int kt64 = tb >> 6;
#pragma unroll
        for (int j = 0; j < 4; ++j) {
            int dim = j * 16 + c;
            float bv = bias[colb + j * 16 + c];
            int rot = (dim & 7) * 8;
#pragma unroll
            for (int i = 0; i < 4; ++i)
#pragma unroll
                for (int r = 0; r < 4; ++r) {
                    int tin = i * 16 + quad * 4 + r;
                    epi[dim * 68 + ((tin + rot) & 63)] = (bf16_t)(acc[i][j][r] + bv);
                }
        }
        bf16_t* dstV = Vt + (size_t)(bidx * HH + hloc) * (TT / 64) * 4096 + (size_t)kt64 * 4096;
#pragma unroll
        for (int it = 0; it < 8; ++it) {
            int dim = it * 8 + rrow;
            int src = ((cchunk + (dim & 7)) & 7) * 8;     // un-rotate
            bf16x8 v = *(const bf16x8*)&epi[dim * 68 + src];
            *(bf16x8*)&dstV[dim * 64 + cchunk * 8] = v;   // 1KB/instr, full lines
        }
    }
}

// ---------------------------------------------------------------- proj GEMM: out f32 = Yb @ WpT^T + bias
__global__ __launch_bounds__(256, 4) void gemm_proj(
        const bf16_t* __restrict__ A, const bf16_t* __restrict__ BT,
        const float* __restrict__ bias, float* __restrict__ Cout) {
    const int K = 768;
    f32x4 acc[4][4] = {};
    GEMM_CORE(A, BT, acc)
#pragma unroll
    for (int j = 0; j < 4; ++j) {
        int col = n0 + wn + j * 16 + c;
        float bv = bias[col];
#pragma unroll
        for (int i = 0; i < 4; ++i) {
            int row = m0 + wm + i * 16 + quad * 4;
#pragma unroll
            for (int r = 0; r < 4; ++r)
                Cout[(size_t)(row + r) * CC + col] = acc[i][j][r] + bv;
        }
    }
}

// ---------------------------------------------------------------- flash attention
// R10 structure (equal-work items + dynamic tail); partials written plain,
// combined by a separate kernel (R12: in-kernel __threadfence semaphore
// REVERTED -- device-scope fence = chip-wide L2 writeback, 3x regression).
__constant__ signed char RK_QT[20] = {11,10,9,8,15,15,7,14,14,13,13,6,12,12,5,4,3,2,1,0};
__constant__ signed char RK_PC[20] = { 2, 2,2,2, 0, 1,2, 0, 1, 0, 1,2, 0, 1,2,2,2,2,2,2};

__global__ __launch_bounds__(256, 3) void flash_attn(
        const bf16_t* __restrict__ Q, const bf16_t* __restrict__ Kc,
        const bf16_t* __restrict__ Vt, bf16_t* __restrict__ Y,
        float* __restrict__ Opart, float* __restrict__ Lpart) {
    // 43KB declared (32KB used): floor(160/43)=3 blocks/CU -> dynamic tail queue
    __shared__ __align__(16) bf16_t smem[22016];
    bf16_t* KsB = smem;            // [2][64*64]
    bf16_t* VsB = smem + 13824;    // [2][64*64] (placed at pad end; full span referenced)

    int blk = blockIdx.x;
    int r = blk / 48, bh = blk - r * 48;   // rank-major: blk 0..47 are the 24-tile items
    int qt = RK_QT[r], pc = RK_PC[r];      // pc: 0=key-half0, 1=key-half1, 2=full chunk
    int kt0 = (pc == 1) ? (qt + 1) : 0;
    int ktend = (pc == 0) ? (qt + 1) : (2 * qt + 2);
    int nct = ktend - kt0;

    int wv = threadIdx.x >> 6, lane = threadIdx.x & 63;
    int b = bh / HH, h = bh - b * HH;
    int q31 = lane & 31, hi = lane >> 5;
    int qbw = qt * 128 + wv * 32;
    const bf16_t* Qg = Q + ((size_t)bh * TT + qbw) * DD;
    const bf16_t* Kg = Kc + (size_t)bh * TT * DD;
    const bf16_t* Vg = Vt + (size_t)bh * (TT / 64) * 4096;

    // Q B-frag: col=q31, k = dk*16 + hi*8 + i (contiguous d per lane)
    bf16x8 qf[4];
#pragma unroll
    for (int dk = 0; dk < 4; ++dk)
        qf[dk] = *(const bf16x8*)(Qg + (size_t)q31 * DD + dk * 16 + hi * 8);

    int srow = wv * 16 + (lane >> 3);
    int slot = lane & 7;
    auto stage = [&](int buf, int kt64) {
#pragma unroll
        for (int ins = 0; ins < 2; ++ins) {
            int rr = srow + ins * 8;
            int g = (slot - (rr & 7)) & 7;
            gload_lds16(Kg + (size_t)(kt64 * 64 + rr) * 64 + g * 8, &KsB[buf * 4096 + (wv * 16 + ins * 8) * 64]);
            gload_lds16(Vg + (size_t)kt64 * 4096 + rr * 64 + g * 8, &VsB[buf * 4096 + (wv * 16 + ins * 8) * 64]);
        }
    };

    f32x16 O[2] = {};            // O^T: col=query=q31, row(d-local)=(r&3)+8*(r>>2)+4*hi, dt*32 offset
    float lsum = 0.0f;

    stage(0, kt0);

#define FA_TILE(FULL)                                                                   \
    {                                                                                   \
        int kt = kt0 + i;                                                               \
        int buf = i & 1;                                                                \
        __syncthreads();                                                                \
        if (i + 1 < nct) stage((i + 1) & 1, kt + 1);                                    \
        _Pragma("unroll")                                                               \
        for (int t32 = 0; t32 < 2; ++t32) {                                             \
            int ks = kt * 64 + t32 * 32;                                                \
            if (!(FULL) && ks > qbw) continue;                                          \
            bool masked = !(FULL) && (ks == qbw);                                       \
            f32x16 st = {};                                                             \
            __builtin_amdgcn_s_setprio(1);                                              \
            _Pragma("unroll")                                                           \
            for (int dk = 0; dk < 4; ++dk) {                                            \
                int row = t32 * 32 + q31;                                               \
                int sl = ((dk * 2 + hi) + (row & 7)) & 7;                               \
                bf16x8 kf = *(const bf16x8*)&KsB[buf * 4096 + row * 64 + sl * 8];       \
                st = __builtin_amdgcn_mfma_f32_32x32x16_bf16(kf, qf[dk], st, 0, 0, 0);  \
            }                                                                           \
            __builtin_amdgcn_s_setprio(0);                                              \
            bf16x8 vf[2][2];                                                            \
            _Pragma("unroll")                                                           \
            for (int dt = 0; dt < 2; ++dt)                                              \
                _Pragma("unroll")                                                       \
                for (int sli = 0; sli < 2; ++sli) {                                     \
                    int row = dt * 32 + q31;                                            \
                    int ch = t32 * 4 + sli * 2 + hi;                                    \
                    int sl = (ch + (row & 7)) & 7;                                      \
                    vf[dt][sli] = *(const bf16x8*)&VsB[buf * 4096 + row * 64 + sl * 8]; \
                }                                                                       \
            float p[16];                                                                \
            _Pragma("unroll")                                                           \
            for (int rr = 0; rr < 16; ++rr) {                                           \
                float e = fast_exp2(st[rr]);                                            \
                if (masked) {                                                           \
                    int keyl = (rr & 3) + 8 * (rr >> 2) + 4 * hi;                       \
                    if (keyl > q31) e = 0.0f;                                           \
                }                                                                       \
                p[rr] = e;                                                              \
            }                                                                           \
            lsum += ((((p[0] + p[1]) + (p[2] + p[3])) + ((p[4] + p[5]) + (p[6] + p[7])))\
                  + (((p[8] + p[9]) + (p[10] + p[11])) + ((p[12] + p[13]) + (p[14] + p[15])))); \
            union { uint32_t u[4]; bf16x8 v; } pb[2];                                   \
            _Pragma("unroll")                                                           \
            for (int sli = 0; sli < 2; ++sli) {                                         \
                uint32_t a0 = pk2(p[sli * 8 + 0], p[sli * 8 + 1]);                      \
                uint32_t b0 = pk2(p[sli * 8 + 2], p[sli * 8 + 3]);                      \
                uint32_t a1 = pk2(p[sli * 8 + 4], p[sli * 8 + 5]);                      \
                uint32_t b1 = pk2(p[sli * 8 + 6], p[sli * 8 + 7]);                      \
                asm("v_permlane32_swap_b32 %0, %1" : "+v"(a0), "+v"(a1));               \
                asm("v_permlane32_swap_b32 %0, %1" : "+v"(b0), "+v"(b1));               \
                pb[sli].u[0] = a0; pb[sli].u[1] = b0; pb[sli].u[2] = a1; pb[sli].u[3] = b1; \
            }                                                                           \
            __builtin_amdgcn_s_setprio(1);                                              \
            _Pragma("unroll")                                                           \
            for (int dt = 0; dt < 2; ++dt) {                                            \
                O[dt] = __builtin_amdgcn_mfma_f32_32x32x16_bf16(vf[dt][0], pb[0].v, O[dt], 0, 0, 0); \
                O[dt] = __builtin_amdgcn_mfma_f32_32x32x16_bf16(vf[dt][1], pb[1].v, O[dt], 0, 0, 0); \
            }                                                                           \
            __builtin_amdgcn_s_setprio(0);                                              \
        }                                                                               \
    }

    int nfull = 2 * qt - kt0;                 // tiles before any mask possible
    if (nfull > nct) nfull = nct;
    if (nfull < 0) nfull = 0;
    int i = 0;
    for (; i < nfull; ++i) FA_TILE(1)         // branch-free interior
    for (; i < nct; ++i) FA_TILE(0)           // causal boundary (<=2 tiles)
#undef FA_TILE

    float l = lsum;
    l += __shfl_xor(l, 32);                   // partner half-lane holds complementary keys

    if (pc == 2) {
        float inv_l = 1.0f / l;
        int row = b * TT + qbw + q31;
#pragma unroll
        for (int dt = 0; dt < 2; ++dt)
#pragma unroll
            for (int g = 0; g < 4; ++g) {
                bf16x4 ov;
#pragma unroll
                for (int rr = 0; rr < 4; ++rr) ov[rr] = (bf16_t)(O[dt][g * 4 + rr] * inv_l);
                *(bf16x4*)(Y + (size_t)row * CC + h * DD + dt * 32 + g * 8 + hi * 4) = ov;
            }
    } else {
        int pslot = bh * 4 + (qt - 12);       // 0..191
        int idx = pslot * 2 + pc;
        float* Op = Opart + ((size_t)idx * 128 + wv * 32 + q31) * 64;
#pragma unroll
        for (int dt = 0; dt < 2; ++dt)
#pragma unroll
            for (int g = 0; g < 4; ++g) {
                f32x4 ov;
#pragma unroll
                for (int rr = 0; rr < 4; ++rr) ov[rr] = O[dt][g * 4 + rr];
                *(f32x4*)(Op + dt * 32 + g * 8 + hi * 4) = ov;
            }
        if (hi == 0) Lpart[idx * 128 + wv * 32 + q31] = l;
    }
}

// ---------------------------------------------------------------- combine split-chunk partials: Y = (O0+O1)/(l0+l1)
__global__ __launch_bounds__(256, 4) void combine_partials(
        const float* __restrict__ Opart, const float* __restrict__ Lpart,
        bf16_t* __restrict__ Y) {
    int pslot = blockIdx.x;                   // 0..191
    int bh = pslot >> 2, qt = 12 + (pslot & 3);
    int b = bh / HH, h = bh - b * HH;
    int t = threadIdx.x;
    int q = t >> 1, dh = (t & 1) * 32;
    const float* p0 = Opart + ((size_t)(pslot * 2 + 0) * 128 + q) * 64 + dh;
    const float* p1 = Opart + ((size_t)(pslot * 2 + 1) * 128 + q) * 64 + dh;
    float inv = 1.0f / (Lpart[(pslot * 2 + 0) * 128 + q] + Lpart[(pslot * 2 + 1) * 128 + q]);
    bf16_t* y = Y + ((size_t)(b * TT + qt * 128 + q)) * CC + h * DD + dh;
#pragma unroll
    for (int g = 0; g < 4; ++g) {
        f32x4 a = *(const f32x4*)(p0 + g * 8);
        f32x4 a2 = *(const f32x4*)(p0 + g * 8 + 4);
        f32x4 c = *(const f32x4*)(p1 + g * 8);
        f32x4 c2 = *(const f32x4*)(p1 + g * 8 + 4);
        bf16x8 o;
#pragma unroll
        for (int rr = 0; rr < 4; ++rr) o[rr] = (bf16_t)((a[rr] + c[rr]) * inv);
#pragma unroll
        for (int rr = 0; rr < 4; ++rr) o[4 + rr] = (bf16_t)((a2[rr] + c2[rr]) * inv);
        *(bf16x8*)(y + g * 8) = o;
    }
}

// ---------------------------------------------------------------- launch
extern "C" void kernel_launch(void* const* d_in, const int* in_sizes, int n_in,
                              void* d_out, int out_size, void* d_ws, size_t ws_size,
                              hipStream_t stream) {
    const float* x      = (const float*)d_in[0];
    const float* W_attn = (const float*)d_in[1];
    const float* b_attn = (const float*)d_in[2];
    const float* W_proj = (const float*)d_in[3];
    const float* b_proj = (const float*)d_in[4];
    float* out = (float*)d_out;

    unsigned char* ws = (unsigned char*)d_ws;
    size_t off = 0;
    auto alloc = [&](size_t bytes) { void* p = ws + off; off += (bytes + 255) & ~(size_t)255; return p; };
    bf16_t* xb  = (bf16_t*)alloc((size_t)MM * CC * 2);
    bf16_t* WaT = (bf16_t*)alloc((size_t)3 * CC * CC * 2);
    bf16_t* WpT = (bf16_t*)alloc((size_t)CC * CC * 2);
    bf16_t* Qh  = (bf16_t*)alloc((size_t)BH * TT * DD * 2);
    bf16_t* Kh  = (bf16_t*)alloc((size_t)BH * TT * DD * 2);
    bf16_t* Vt  = (bf16_t*)alloc((size_t)BH * TT * DD * 2);
    bf16_t* Yb  = (bf16_t*)alloc((size_t)MM * CC * 2);
    float*  Opart = (float*)alloc((size_t)192 * 2 * 128 * 64 * 4);
    float*  Lpart = (float*)alloc((size_t)192 * 2 * 128 * 4);
    float*  trig  = (float*)alloc((size_t)2 * 32 * 2048 * 4);

    prep<<<dim3(6144 + 1728 + 576 + 64), 256, 0, stream>>>(x, W_attn, W_proj, xb, WaT, WpT, trig);
    gemm_qkv<<<dim3(MM / 128, 3 * CC / 128), 256, 0, stream>>>(xb, WaT, b_attn, trig, Qh, Kh, Vt);
    flash_attn<<<dim3(960), 256, 0, stream>>>(Qh, Kh, Vt, Yb, Opart, Lpart);
    combine_partials<<<dim3(192), 256, 0, stream>>>(Opart, Lpart, Yb);
    gemm_proj<<<dim3(MM / 128, CC / 128), 256, 0, stream>>>(Yb, WpT, b_proj, out);
}